// Round 18
// baseline (56.024 us; speedup 1.0000x reference)
//
#include <hip/hip_runtime.h>

#pragma clang fp contract(off)

#define TDIM 256
#define CDIM 64
#define SENT (-1e30f)
#define NPART 512           // absmax stage-1 blocks == partial count
#define WS_PART_OFF 16      // float offset of partials in d_ws
#define VSTR 272            // vbf row stride in shorts (544 B, 16B-aligned rows)

typedef __attribute__((ext_vector_type(8))) short bf16x8;
typedef __attribute__((ext_vector_type(4))) float f32x4;
typedef __attribute__((ext_vector_type(4))) int i32x4;

static constexpr float BOA = (float)(0.96963238 / 0.35815147);
static constexpr float COA = (float)(1.0 / 0.35815147);
static constexpr float AF  = 0.35815147f;
static constexpr float X0F = -0.6931f;

// Markstein exact division: r = RN(1/d) precomputed -> correctly-rounded IEEE
// quotient for our (normal-range) operands, bit-identical to '/'.
__device__ __forceinline__ float exdiv(float x, float d, float r) {
  float q0 = x * r;
  float e = __builtin_fmaf(-d, q0, x);
  return __builtin_fmaf(e, r, q0);
}

__device__ __forceinline__ float q8f(float x, float s, float rs) {
  float t = rintf(exdiv(x, s, rs));
  return fminf(fmaxf(t, -128.f), 127.f);   // quantized value as exact float
}

__device__ __forceinline__ int pack4q(float4 f, float s, float rs) {
  unsigned a = (unsigned)(int)q8f(f.x, s, rs) & 255u;
  unsigned b = (unsigned)(int)q8f(f.y, s, rs) & 255u;
  unsigned c = (unsigned)(int)q8f(f.z, s, rs) & 255u;
  unsigned d = (unsigned)(int)q8f(f.w, s, rs) & 255u;
  return (int)(a | (b << 8) | (c << 16) | (d << 24));
}

__device__ __forceinline__ unsigned f2bfu(float f) {
  // exact truncation for integer-valued |f| <= 256 (<= 9 significant bits)
  return __float_as_uint(f) >> 16;
}

__device__ __forceinline__ bf16x8 mk_bf16x8(unsigned a0, unsigned a1,
                                            unsigned a2, unsigned a3) {
  union { unsigned u[4]; bf16x8 h; } t;
  t.u[0] = a0; t.u[1] = a1; t.u[2] = a2; t.u[3] = a3;
  return t.h;
}

// k-label -> permuted V^T storage position: lane (hi) PV-reads become one
// contiguous 16B ds_read_b128 at shorts [32ks+8hi, +8).
__device__ __forceinline__ int vperm(int k) {
  return (k & ~31) | (((k & 15) >> 2) << 3) | (((k >> 4) & 1) << 2) | (k & 3);
}

// ---- absmax stage 1: per-block partials, no atomics ----
__global__ __launch_bounds__(256) void absmax_partial_kernel(
    const float4* __restrict__ q, const float4* __restrict__ k,
    const float4* __restrict__ v, float* __restrict__ ws, int n4) {
  __shared__ float red[3][4];
  int tid = blockIdx.x * 256 + threadIdx.x;
  int stride = gridDim.x * 256;
  float m0 = 0.f, m1 = 0.f, m2 = 0.f;
  for (int i = tid; i < n4; i += stride) {
    float4 a = q[i];
    m0 = fmaxf(m0, fmaxf(fmaxf(fabsf(a.x), fabsf(a.y)), fmaxf(fabsf(a.z), fabsf(a.w))));
    float4 b = k[i];
    m1 = fmaxf(m1, fmaxf(fmaxf(fabsf(b.x), fabsf(b.y)), fmaxf(fabsf(b.z), fabsf(b.w))));
    float4 c = v[i];
    m2 = fmaxf(m2, fmaxf(fmaxf(fabsf(c.x), fabsf(c.y)), fmaxf(fabsf(c.z), fabsf(c.w))));
  }
#pragma unroll
  for (int off = 32; off > 0; off >>= 1) {
    m0 = fmaxf(m0, __shfl_xor(m0, off, 64));
    m1 = fmaxf(m1, __shfl_xor(m1, off, 64));
    m2 = fmaxf(m2, __shfl_xor(m2, off, 64));
  }
  int wave = threadIdx.x >> 6;
  if ((threadIdx.x & 63) == 0) {
    red[0][wave] = m0; red[1][wave] = m1; red[2][wave] = m2;
  }
  __syncthreads();
  if (threadIdx.x == 0) {
    ws[WS_PART_OFF + 0 * NPART + blockIdx.x] = fmaxf(fmaxf(red[0][0], red[0][1]), fmaxf(red[0][2], red[0][3]));
    ws[WS_PART_OFF + 1 * NPART + blockIdx.x] = fmaxf(fmaxf(red[1][0], red[1][1]), fmaxf(red[1][2], red[1][3]));
    ws[WS_PART_OFF + 2 * NPART + blockIdx.x] = fmaxf(fmaxf(red[2][0], red[2][1]), fmaxf(red[2][2], red[2][3]));
  }
}

// one block = one batch, 512 threads (8 waves); wave w owns tiles {w, 15-w}.
// Prologue reduces the NPART partials itself (max is order-exact).
__global__ __launch_bounds__(512, 4) void head_kernel(
    const float* __restrict__ qg, const float* __restrict__ kg,
    const float* __restrict__ vg, const float* __restrict__ ws,
    float* __restrict__ out, int out_size) {
  // K int8 in MFMA frag order: word idx = tile*256 + lane*4 + w (16 KB)
  __shared__ __align__(16) int kf[4096];
  // V^T as bf16, k-permuted (vperm) so PV is one b128/lane: rows 544 B.
  __shared__ __align__(16) unsigned short vbf[CDIM][VSTR];
  __shared__ float redmax[3][8];

  const int tid = threadIdx.x;
  const int b = blockIdx.x;
  const int lane = tid & 63;
  const int wave = tid >> 6;          // 0..7
  const int hi = lane >> 4;
  const int s15 = lane & 15;

  // ---- reduce absmax partials (order-exact max -> identical scales) ----
  {
    float v0 = ws[WS_PART_OFF + 0 * NPART + tid];
    float v1 = ws[WS_PART_OFF + 1 * NPART + tid];
    float v2 = ws[WS_PART_OFF + 2 * NPART + tid];
#pragma unroll
    for (int off = 32; off > 0; off >>= 1) {
      v0 = fmaxf(v0, __shfl_xor(v0, off, 64));
      v1 = fmaxf(v1, __shfl_xor(v1, off, 64));
      v2 = fmaxf(v2, __shfl_xor(v2, off, 64));
    }
    if (lane == 0) { redmax[0][wave] = v0; redmax[1][wave] = v1; redmax[2][wave] = v2; }
  }
  __syncthreads();
  float qmax = redmax[0][0], kmax = redmax[1][0], vmax = redmax[2][0];
#pragma unroll
  for (int i = 1; i < 8; ++i) {
    qmax = fmaxf(qmax, redmax[0][i]);
    kmax = fmaxf(kmax, redmax[1][i]);
    vmax = fmaxf(vmax, redmax[2][i]);
  }

  // uniform scale pipeline constants (replicate reference f32 op order exactly)
  const float qsf = qmax / 127.f;
  const float ksf = kmax / 127.f;
  const float vsf = vmax / 127.f;
  const float sf = ksf * qsf;
  const float x0i = floorf(X0F / sf);
  const float bint = floorf(BOA / sf);
  const float cint = floorf(COA / (sf * sf));
  const float esf = ((AF * sf) * sf) * 0x1p-30f;
  const float emax = (cint * 0x1p30f) * esf;
  const float s16 = emax / 32767.f;
  const float clampv = 30.f * x0i;
  const float rq = 1.f / qsf, rk = 1.f / ksf, rv = 1.f / vsf;
  const float rx0 = 1.f / x0i;
  const float essr = esf / s16;       // fused QuantAct(16) scale
  const float nx0i = -x0i;            // for the exact fma form of rr

  // ---- stage K (i8 frag order) and V^T (bf16, k-permuted rows) ----
  const float4* q4 = (const float4*)(qg + (size_t)b * (TDIM * CDIM));
  const float4* k4 = (const float4*)(kg + (size_t)b * (TDIM * CDIM));
  const float4* v4 = (const float4*)(vg + (size_t)b * (TDIM * CDIM));
#pragma unroll
  for (int i = 0; i < 8; ++i) {
    int vidx = i * 512 + tid;
    int row = vidx >> 4, cw = vidx & 15;
    int fidx = ((row >> 4) << 8) + ((row & 15) << 2) + ((cw >> 2) << 6) + (cw & 3);
    float4 f = k4[vidx];
    kf[fidx] = pack4q(f, ksf, rk);
    f = v4[vidx];
    int c0 = cw << 2;
    int prow = vperm(row);
    vbf[c0 + 0][prow] = (unsigned short)f2bfu(q8f(f.x, vsf, rv));
    vbf[c0 + 1][prow] = (unsigned short)f2bfu(q8f(f.y, vsf, rv));
    vbf[c0 + 2][prow] = (unsigned short)f2bfu(q8f(f.z, vsf, rv));
    vbf[c0 + 3][prow] = (unsigned short)f2bfu(q8f(f.w, vsf, rv));
  }
  __syncthreads();   // kf/vbf read-only afterwards

  const i32x4 zero4 = {0, 0, 0, 0};

  // Q raw prefetch for tile 0 (R = wave)
  float4 qldA, qldB, qldC, qldD;
  {
    const float4* p = q4 + ((wave << 4) + s15) * 16 + (hi << 2);
    qldA = p[0]; qldB = p[1]; qldC = p[2]; qldD = p[3];
  }

  // ---- main loop: 2 balanced tiles per wave: {w, 15-w} (cost 17 each) ----
#pragma unroll 1
  for (int itt = 0; itt < 2; ++itt) {
    const int R = itt ? (15 - wave) : wave;

    i32x4 aQ;
    aQ[0] = pack4q(qldA, qsf, rq);
    aQ[1] = pack4q(qldB, qsf, rq);
    aQ[2] = pack4q(qldC, qsf, rq);
    aQ[3] = pack4q(qldD, qsf, rq);

    // swapped QK^T: lane holds ONE q-row (s15); k = Cc*16 + hi*4 + j.
    float xi[16][4];
    float mxr = SENT;
#pragma unroll
    for (int Cc = 0; Cc < 16; ++Cc) {
      if (Cc < R) {
        i32x4 bK = *(const i32x4*)(kf + (Cc << 8) + (lane << 2));
        i32x4 d = __builtin_amdgcn_mfma_i32_16x16x64_i8(bK, aQ, zero4, 0, 0, 0);
#pragma unroll
        for (int j = 0; j < 4; ++j) xi[Cc][j] = (float)d[j] * 0.125f;
        mxr = fmaxf(mxr, fmaxf(fmaxf(xi[Cc][0], xi[Cc][1]),
                               fmaxf(xi[Cc][2], xi[Cc][3])));
      } else if (Cc == R) {
        i32x4 bK = *(const i32x4*)(kf + (Cc << 8) + (lane << 2));
        i32x4 d = __builtin_amdgcn_mfma_i32_16x16x64_i8(bK, aQ, zero4, 0, 0, 0);
#pragma unroll
        for (int j = 0; j < 4; ++j) {
          bool act = ((hi << 2) + j) <= s15;        // k_local <= q_local
          xi[Cc][j] = act ? (float)d[j] * 0.125f : SENT;
        }
        mxr = fmaxf(mxr, fmaxf(fmaxf(xi[Cc][0], xi[Cc][1]),
                               fmaxf(xi[Cc][2], xi[Cc][3])));
      }
    }
    float mx = fmaxf(mxr, __shfl_xor(mxr, 16, 64));
    mx = fmaxf(mx, __shfl_xor(mx, 32, 64));

    // ---- integer-softmax pipeline. qv division stays Markstein-exact.
    //      rr via fma is EXACT-identical (both operands exact multiples of
    //      1/8 below 2^24); poly via fma differs only in 1-ulp double
    //      rounding (same accepted class as the essr fusion).
    float lsr = 0.f;
#pragma unroll
    for (int Cc = 0; Cc < 16; ++Cc) {
      if (Cc <= R) {
#pragma unroll
        for (int j = 0; j < 4; ++j) {
          float x = xi[Cc][j] - mx;                 // masked: -1e30, clamp catches
          x = fmaxf(x, clampv);
          float qv = floorf(exdiv(x, x0i, rx0));
          float rr = __builtin_fmaf(nx0i, qv, x);   // exact
          float poly = __builtin_fmaf(rr + bint, rr, cint);
          int iq = (int)qv;                         // in [0,30]
          float p2 = __int_as_float((157 - iq) << 23);  // exact 2^(30-q)
          float ef = fmaxf(floorf(poly * p2), 0.f);
          float v16 = fminf(rintf(ef * essr), 32767.f);
          xi[Cc][j] = v16;                          // masked -> exactly 0
          lsr += v16;
        }
      }
    }
    float lsum = lsr + __shfl_xor(lsr, 16, 64);
    lsum += __shfl_xor(lsum, 32, 64);

    float factor = floorf(4294967296.f / lsum);
    const float factor24 = factor * 0x1p-24f;

    // prefetch next tile's raw Q during PV (covers L2/L3 latency; live range
    // limited to the PV section -> fits under the 128-reg cap)
    if (itt == 0) {
      const float4* p = q4 + (((15 - wave) << 4) + s15) * 16 + (hi << 2);
      qldA = p[0]; qldB = p[1]; qldC = p[2]; qldD = p[3];
    }

    // ---- PV with W-pack fused per ks; B is ONE b128 per (ks,g) via vperm.
    const int ksn = (R + 2) >> 1;
    f32x4 acc[4] = {{0.f, 0.f, 0.f, 0.f}, {0.f, 0.f, 0.f, 0.f},
                    {0.f, 0.f, 0.f, 0.f}, {0.f, 0.f, 0.f, 0.f}};
    __builtin_amdgcn_s_setprio(1);
#pragma unroll
    for (int ks = 0; ks < 8; ++ks) {
      if (ks < ksn) {
        const int c0 = 2 * ks, c1 = 2 * ks + 1;
        unsigned a0 = f2bfu(floorf(xi[c0][0] * factor24)) |
                      (f2bfu(floorf(xi[c0][1] * factor24)) << 16);
        unsigned a1 = f2bfu(floorf(xi[c0][2] * factor24)) |
                      (f2bfu(floorf(xi[c0][3] * factor24)) << 16);
        unsigned a2 = 0, a3 = 0;
        if (c1 <= R) {
          a2 = f2bfu(floorf(xi[c1][0] * factor24)) |
               (f2bfu(floorf(xi[c1][1] * factor24)) << 16);
          a3 = f2bfu(floorf(xi[c1][2] * factor24)) |
               (f2bfu(floorf(xi[c1][3] * factor24)) << 16);
        }
        bf16x8 af = mk_bf16x8(a0, a1, a2, a3);
#pragma unroll
        for (int g = 0; g < 4; ++g) {
          const bf16x8* pb =
              (const bf16x8*)&vbf[(g << 4) + s15][(ks << 5) + (hi << 3)];
          acc[g] = __builtin_amdgcn_mfma_f32_16x16x32_bf16(af, *pb, acc[g], 0, 0, 0);
        }
      }
    }
    __builtin_amdgcn_s_setprio(0);

    // ---- out: rows R*16 + hi*4 + j, channels g*16 + s15 ----
    const int rb = (R << 4) + (hi << 2);
#pragma unroll
    for (int g = 0; g < 4; ++g)
#pragma unroll
      for (int j = 0; j < 4; ++j)
        out[((b * TDIM) + rb + j) * CDIM + (g << 4) + s15] = (acc[g][j] * vsf) * 0x1p-16f;
  }

  if (b == 0 && tid == 0) out[out_size - 1] = 0.00390625f;  // wei_sf
}

extern "C" void kernel_launch(void* const* d_in, const int* in_sizes, int n_in,
                              void* d_out, int out_size, void* d_ws, size_t ws_size,
                              hipStream_t stream) {
  const float* q = (const float*)d_in[0];
  const float* k = (const float*)d_in[1];
  const float* v = (const float*)d_in[2];
  float* out = (float*)d_out;
  float* ws = (float*)d_ws;
  int n = in_sizes[0];               // B*T*C = 8388608
  int nb = n / (TDIM * CDIM);        // 512 batches

  absmax_partial_kernel<<<NPART, 256, 0, stream>>>((const float4*)q, (const float4*)k,
                                                   (const float4*)v, ws, n / 4);
  head_kernel<<<nb, 512, 0, stream>>>(q, k, v, (const float*)d_ws, out, out_size);
}

// Round 19
// 50.662 us; speedup vs baseline: 1.1058x; 1.1058x over previous
//
#include <hip/hip_runtime.h>

#pragma clang fp contract(off)

#define TDIM 256
#define CDIM 64
#define SENT (-1e30f)
#define NPART 512           // absmax stage-1 blocks == partial count
#define WS_PART_OFF 16      // float offset of partials in d_ws
#define VSTR 272            // vbf row stride in shorts (544 B, 16B-aligned rows)

typedef __attribute__((ext_vector_type(8))) short bf16x8;
typedef __attribute__((ext_vector_type(4))) float f32x4;
typedef __attribute__((ext_vector_type(4))) int i32x4;

static constexpr float BOA = (float)(0.96963238 / 0.35815147);
static constexpr float COA = (float)(1.0 / 0.35815147);
static constexpr float AF  = 0.35815147f;
static constexpr float X0F = -0.6931f;

// Markstein exact division: r = RN(1/d) precomputed -> correctly-rounded IEEE
// quotient for our (normal-range) operands, bit-identical to '/'.
__device__ __forceinline__ float exdiv(float x, float d, float r) {
  float q0 = x * r;
  float e = __builtin_fmaf(-d, q0, x);
  return __builtin_fmaf(e, r, q0);
}

__device__ __forceinline__ float q8f(float x, float s, float rs) {
  float t = rintf(exdiv(x, s, rs));
  return fminf(fmaxf(t, -128.f), 127.f);   // quantized value as exact float
}

__device__ __forceinline__ int pack4q(float4 f, float s, float rs) {
  unsigned a = (unsigned)(int)q8f(f.x, s, rs) & 255u;
  unsigned b = (unsigned)(int)q8f(f.y, s, rs) & 255u;
  unsigned c = (unsigned)(int)q8f(f.z, s, rs) & 255u;
  unsigned d = (unsigned)(int)q8f(f.w, s, rs) & 255u;
  return (int)(a | (b << 8) | (c << 16) | (d << 24));
}

__device__ __forceinline__ unsigned f2bfu(float f) {
  // exact truncation for integer-valued |f| <= 256 (<= 9 significant bits)
  return __float_as_uint(f) >> 16;
}

__device__ __forceinline__ bf16x8 mk_bf16x8(unsigned a0, unsigned a1,
                                            unsigned a2, unsigned a3) {
  union { unsigned u[4]; bf16x8 h; } t;
  t.u[0] = a0; t.u[1] = a1; t.u[2] = a2; t.u[3] = a3;
  return t.h;
}

// k-label -> permuted V^T storage position: lane (hi) PV-reads become one
// contiguous 16B ds_read_b128 at shorts [32ks+8hi, +8).
__device__ __forceinline__ int vperm(int k) {
  return (k & ~31) | (((k & 15) >> 2) << 3) | (((k >> 4) & 1) << 2) | (k & 3);
}

// ---- absmax stage 1: per-block partials, no atomics ----
__global__ __launch_bounds__(256) void absmax_partial_kernel(
    const float4* __restrict__ q, const float4* __restrict__ k,
    const float4* __restrict__ v, float* __restrict__ ws, int n4) {
  __shared__ float red[3][4];
  int tid = blockIdx.x * 256 + threadIdx.x;
  int stride = gridDim.x * 256;
  float m0 = 0.f, m1 = 0.f, m2 = 0.f;
  for (int i = tid; i < n4; i += stride) {
    float4 a = q[i];
    m0 = fmaxf(m0, fmaxf(fmaxf(fabsf(a.x), fabsf(a.y)), fmaxf(fabsf(a.z), fabsf(a.w))));
    float4 b = k[i];
    m1 = fmaxf(m1, fmaxf(fmaxf(fabsf(b.x), fabsf(b.y)), fmaxf(fabsf(b.z), fabsf(b.w))));
    float4 c = v[i];
    m2 = fmaxf(m2, fmaxf(fmaxf(fabsf(c.x), fabsf(c.y)), fmaxf(fabsf(c.z), fabsf(c.w))));
  }
#pragma unroll
  for (int off = 32; off > 0; off >>= 1) {
    m0 = fmaxf(m0, __shfl_xor(m0, off, 64));
    m1 = fmaxf(m1, __shfl_xor(m1, off, 64));
    m2 = fmaxf(m2, __shfl_xor(m2, off, 64));
  }
  int wave = threadIdx.x >> 6;
  if ((threadIdx.x & 63) == 0) {
    red[0][wave] = m0; red[1][wave] = m1; red[2][wave] = m2;
  }
  __syncthreads();
  if (threadIdx.x == 0) {
    ws[WS_PART_OFF + 0 * NPART + blockIdx.x] = fmaxf(fmaxf(red[0][0], red[0][1]), fmaxf(red[0][2], red[0][3]));
    ws[WS_PART_OFF + 1 * NPART + blockIdx.x] = fmaxf(fmaxf(red[1][0], red[1][1]), fmaxf(red[1][2], red[1][3]));
    ws[WS_PART_OFF + 2 * NPART + blockIdx.x] = fmaxf(fmaxf(red[2][0], red[2][1]), fmaxf(red[2][2], red[2][3]));
  }
}

// one block = one batch, 512 threads (8 waves); wave w owns tiles {w, 15-w}.
// Prologue reduces the NPART partials itself (max is order-exact).
__global__ __launch_bounds__(512, 4) void head_kernel(
    const float* __restrict__ qg, const float* __restrict__ kg,
    const float* __restrict__ vg, const float* __restrict__ ws,
    float* __restrict__ out, int out_size) {
  // K int8 in MFMA frag order: word idx = tile*256 + lane*4 + w (16 KB)
  __shared__ __align__(16) int kf[4096];
  // V^T as bf16, k-permuted (vperm) so PV is one b128/lane: rows 544 B.
  __shared__ __align__(16) unsigned short vbf[CDIM][VSTR];
  __shared__ float redmax[3][8];

  const int tid = threadIdx.x;
  const int b = blockIdx.x;
  const int lane = tid & 63;
  const int wave = tid >> 6;          // 0..7
  const int hi = lane >> 4;
  const int s15 = lane & 15;

  // ---- reduce absmax partials (order-exact max -> identical scales) ----
  {
    float v0 = ws[WS_PART_OFF + 0 * NPART + tid];
    float v1 = ws[WS_PART_OFF + 1 * NPART + tid];
    float v2 = ws[WS_PART_OFF + 2 * NPART + tid];
#pragma unroll
    for (int off = 32; off > 0; off >>= 1) {
      v0 = fmaxf(v0, __shfl_xor(v0, off, 64));
      v1 = fmaxf(v1, __shfl_xor(v1, off, 64));
      v2 = fmaxf(v2, __shfl_xor(v2, off, 64));
    }
    if (lane == 0) { redmax[0][wave] = v0; redmax[1][wave] = v1; redmax[2][wave] = v2; }
  }
  __syncthreads();
  float qmax = redmax[0][0], kmax = redmax[1][0], vmax = redmax[2][0];
#pragma unroll
  for (int i = 1; i < 8; ++i) {
    qmax = fmaxf(qmax, redmax[0][i]);
    kmax = fmaxf(kmax, redmax[1][i]);
    vmax = fmaxf(vmax, redmax[2][i]);
  }

  // uniform scale pipeline constants (replicate reference f32 op order exactly)
  const float qsf = qmax / 127.f;
  const float ksf = kmax / 127.f;
  const float vsf = vmax / 127.f;
  const float sf = ksf * qsf;
  const float x0i = floorf(X0F / sf);
  const float bint = floorf(BOA / sf);
  const float cint = floorf(COA / (sf * sf));
  const float esf = ((AF * sf) * sf) * 0x1p-30f;
  const float emax = (cint * 0x1p30f) * esf;
  const float s16 = emax / 32767.f;
  const float clampv = 30.f * x0i;
  const float rq = 1.f / qsf, rk = 1.f / ksf, rv = 1.f / vsf;
  const float rx0 = 1.f / x0i;
  const float essr = esf / s16;       // fused QuantAct(16) scale
  const float nx0i = -x0i;            // for the exact fma form of rr

  // ---- stage K (i8 frag order) and V^T (bf16, k-permuted rows) ----
  const float4* q4 = (const float4*)(qg + (size_t)b * (TDIM * CDIM));
  const float4* k4 = (const float4*)(kg + (size_t)b * (TDIM * CDIM));
  const float4* v4 = (const float4*)(vg + (size_t)b * (TDIM * CDIM));
#pragma unroll
  for (int i = 0; i < 8; ++i) {
    int vidx = i * 512 + tid;
    int row = vidx >> 4, cw = vidx & 15;
    int fidx = ((row >> 4) << 8) + ((row & 15) << 2) + ((cw >> 2) << 6) + (cw & 3);
    float4 f = k4[vidx];
    kf[fidx] = pack4q(f, ksf, rk);
    f = v4[vidx];
    int c0 = cw << 2;
    int prow = vperm(row);
    vbf[c0 + 0][prow] = (unsigned short)f2bfu(q8f(f.x, vsf, rv));
    vbf[c0 + 1][prow] = (unsigned short)f2bfu(q8f(f.y, vsf, rv));
    vbf[c0 + 2][prow] = (unsigned short)f2bfu(q8f(f.z, vsf, rv));
    vbf[c0 + 3][prow] = (unsigned short)f2bfu(q8f(f.w, vsf, rv));
  }
  __syncthreads();   // kf/vbf read-only afterwards

  const i32x4 zero4 = {0, 0, 0, 0};

  // ---- main loop: 2 balanced tiles per wave: {w, 15-w} (cost 17 each) ----
#pragma unroll 1
  for (int itt = 0; itt < 2; ++itt) {
    const int R = itt ? (15 - wave) : wave;

    // Q loaded at use (L2/L3-warm; TLP at 4 waves/SIMD hides it).
    // NOTE r18 lesson: an earlier prefetch costs 16 live regs through the
    // softmax body -> spill at the 128 cap. Keep at-use.
    i32x4 aQ;
    {
      const float4* p = q4 + ((R << 4) + s15) * 16 + (hi << 2);
      aQ[0] = pack4q(p[0], qsf, rq);
      aQ[1] = pack4q(p[1], qsf, rq);
      aQ[2] = pack4q(p[2], qsf, rq);
      aQ[3] = pack4q(p[3], qsf, rq);
    }

    // swapped QK^T: lane holds ONE q-row (s15); k = Cc*16 + hi*4 + j.
    float xi[16][4];
    float mxr = SENT;
#pragma unroll
    for (int Cc = 0; Cc < 16; ++Cc) {
      if (Cc < R) {
        i32x4 bK = *(const i32x4*)(kf + (Cc << 8) + (lane << 2));
        i32x4 d = __builtin_amdgcn_mfma_i32_16x16x64_i8(bK, aQ, zero4, 0, 0, 0);
#pragma unroll
        for (int j = 0; j < 4; ++j) xi[Cc][j] = (float)d[j] * 0.125f;
        mxr = fmaxf(mxr, fmaxf(fmaxf(xi[Cc][0], xi[Cc][1]),
                               fmaxf(xi[Cc][2], xi[Cc][3])));
      } else if (Cc == R) {
        i32x4 bK = *(const i32x4*)(kf + (Cc << 8) + (lane << 2));
        i32x4 d = __builtin_amdgcn_mfma_i32_16x16x64_i8(bK, aQ, zero4, 0, 0, 0);
#pragma unroll
        for (int j = 0; j < 4; ++j) {
          bool act = ((hi << 2) + j) <= s15;        // k_local <= q_local
          xi[Cc][j] = act ? (float)d[j] * 0.125f : SENT;
        }
        mxr = fmaxf(mxr, fmaxf(fmaxf(xi[Cc][0], xi[Cc][1]),
                               fmaxf(xi[Cc][2], xi[Cc][3])));
      }
    }
    float mx = fmaxf(mxr, __shfl_xor(mxr, 16, 64));
    mx = fmaxf(mx, __shfl_xor(mx, 32, 64));

    // ---- integer-softmax pipeline. qv division stays Markstein-exact.
    //      rr via fma is EXACT-identical; poly via fma 1-ulp class (both
    //      measured absmax-neutral in r18).
    float lsr = 0.f;
#pragma unroll
    for (int Cc = 0; Cc < 16; ++Cc) {
      if (Cc <= R) {
#pragma unroll
        for (int j = 0; j < 4; ++j) {
          float x = xi[Cc][j] - mx;                 // masked: -1e30, clamp catches
          x = fmaxf(x, clampv);
          float qv = floorf(exdiv(x, x0i, rx0));
          float rr = __builtin_fmaf(nx0i, qv, x);   // exact
          float poly = __builtin_fmaf(rr + bint, rr, cint);
          int iq = (int)qv;                         // in [0,30]
          float p2 = __int_as_float((157 - iq) << 23);  // exact 2^(30-q)
          float ef = fmaxf(floorf(poly * p2), 0.f);
          float v16 = fminf(rintf(ef * essr), 32767.f);
          xi[Cc][j] = v16;                          // masked -> exactly 0
          lsr += v16;
        }
      }
    }
    float lsum = lsr + __shfl_xor(lsr, 16, 64);
    lsum += __shfl_xor(lsum, 32, 64);

    float factor = floorf(4294967296.f / lsum);
    const float factor24 = factor * 0x1p-24f;

    // ---- PV with W-pack fused per ks; B is ONE b128 per (ks,g) via vperm.
    const int ksn = (R + 2) >> 1;
    f32x4 acc[4] = {{0.f, 0.f, 0.f, 0.f}, {0.f, 0.f, 0.f, 0.f},
                    {0.f, 0.f, 0.f, 0.f}, {0.f, 0.f, 0.f, 0.f}};
    __builtin_amdgcn_s_setprio(1);
#pragma unroll
    for (int ks = 0; ks < 8; ++ks) {
      if (ks < ksn) {
        const int c0 = 2 * ks, c1 = 2 * ks + 1;
        unsigned a0 = f2bfu(floorf(xi[c0][0] * factor24)) |
                      (f2bfu(floorf(xi[c0][1] * factor24)) << 16);
        unsigned a1 = f2bfu(floorf(xi[c0][2] * factor24)) |
                      (f2bfu(floorf(xi[c0][3] * factor24)) << 16);
        unsigned a2 = 0, a3 = 0;
        if (c1 <= R) {
          a2 = f2bfu(floorf(xi[c1][0] * factor24)) |
               (f2bfu(floorf(xi[c1][1] * factor24)) << 16);
          a3 = f2bfu(floorf(xi[c1][2] * factor24)) |
               (f2bfu(floorf(xi[c1][3] * factor24)) << 16);
        }
        bf16x8 af = mk_bf16x8(a0, a1, a2, a3);
#pragma unroll
        for (int g = 0; g < 4; ++g) {
          const bf16x8* pb =
              (const bf16x8*)&vbf[(g << 4) + s15][(ks << 5) + (hi << 3)];
          acc[g] = __builtin_amdgcn_mfma_f32_16x16x32_bf16(af, *pb, acc[g], 0, 0, 0);
        }
      }
    }
    __builtin_amdgcn_s_setprio(0);

    // ---- out: rows R*16 + hi*4 + j, channels g*16 + s15 ----
    const int rb = (R << 4) + (hi << 2);
#pragma unroll
    for (int g = 0; g < 4; ++g)
#pragma unroll
      for (int j = 0; j < 4; ++j)
        out[((b * TDIM) + rb + j) * CDIM + (g << 4) + s15] = (acc[g][j] * vsf) * 0x1p-16f;
  }

  if (b == 0 && tid == 0) out[out_size - 1] = 0.00390625f;  // wei_sf
}

extern "C" void kernel_launch(void* const* d_in, const int* in_sizes, int n_in,
                              void* d_out, int out_size, void* d_ws, size_t ws_size,
                              hipStream_t stream) {
  const float* q = (const float*)d_in[0];
  const float* k = (const float*)d_in[1];
  const float* v = (const float*)d_in[2];
  float* out = (float*)d_out;
  float* ws = (float*)d_ws;
  int n = in_sizes[0];               // B*T*C = 8388608
  int nb = n / (TDIM * CDIM);        // 512 batches

  absmax_partial_kernel<<<NPART, 256, 0, stream>>>((const float4*)q, (const float4*)k,
                                                   (const float4*)v, ws, n / 4);
  head_kernel<<<nb, 512, 0, stream>>>(q, k, v, (const float*)d_ws, out, out_size);
}